// Round 1
// 135.230 us; speedup vs baseline: 1.0600x; 1.0600x over previous
//
#include <hip/hip_runtime.h>
#include <stdint.h>

typedef _Float16 half8 __attribute__((ext_vector_type(8)));
typedef float floatx4 __attribute__((ext_vector_type(4)));

// ---------------------------------------------------------------------------
// Threefry-2x32, 20 rounds (JAX-compatible, partitionable variant)
// R6: rotl forced to v_alignbit_b32 via builtin (guaranteed 1 instr/rotate).
// ---------------------------------------------------------------------------
__device__ __forceinline__ uint32_t rotl32(uint32_t v, int r) {
  return __builtin_amdgcn_alignbit(v, v, 32 - r);  // (v:v)>>(32-r) == rotl
}

__device__ __forceinline__ void threefry2x32(uint32_t k0, uint32_t k1,
                                             uint32_t x0, uint32_t x1,
                                             uint32_t& o0, uint32_t& o1) {
  uint32_t k2 = k0 ^ k1 ^ 0x1BD11BDAu;
  x0 += k0; x1 += k1;
#define TF_R(r) { x0 += x1; x1 = rotl32(x1, (r)); x1 ^= x0; }
  TF_R(13) TF_R(15) TF_R(26) TF_R(6)   x0 += k1; x1 += k2 + 1u;
  TF_R(17) TF_R(29) TF_R(16) TF_R(24)  x0 += k2; x1 += k0 + 2u;
  TF_R(13) TF_R(15) TF_R(26) TF_R(6)   x0 += k0; x1 += k1 + 3u;
  TF_R(17) TF_R(29) TF_R(16) TF_R(24)  x0 += k1; x1 += k2 + 4u;
  TF_R(13) TF_R(15) TF_R(26) TF_R(6)   x0 += k2; x1 += k0 + 5u;
#undef TF_R
  o0 = x0; o1 = x1;
}

// ---------------------------------------------------------------------------
// Noise multiplier: nm = 1 + 0.01*sqrt(2)*erfinv(u), u from JAX threefry bits.
// R6 changes vs validated R2-R5 erfinv_fast:
//  - (bits>>9)|0x3f800000 via one v_alignbit (0x7f<<23 == 0x3f800000).
//  - log2 domain: a = fma(log2(t), -ln2, -2.5) saves the separate -ln(t) mul.
//  - central Giles poly truncated 9 -> 5 coeffs. Dropped-term bound at
//    |a|<=2.5: 2.8e-8*2.5^8 + 3.4e-7*2.5^7 + 3.5e-6*2.5^6 + 4.4e-6*2.5^5
//    ~= 1.6e-3 on erfinv -> ~2e-6 on the normalized output (budget 4.9e-4).
//  - tail branch (|u| > 0.99664, ~0.3% of elems) keeps the full 9-coef poly.
// NOTE (R4 NaN post-mortem, still applies): clamp u > -1 is REQUIRED; all-zero
// mantissa bits give u = -1 -> log(0) -> -inf -> NaN through the norm.
// ---------------------------------------------------------------------------
__device__ __forceinline__ float noise_mult(uint32_t ka0, uint32_t ka1,
                                            uint32_t idx) {
  uint32_t o0, o1;
  threefry2x32(ka0, ka1, 0u, idx, o0, o1);
  uint32_t bits = o0 ^ o1;
  float vf = __uint_as_float(__builtin_amdgcn_alignbit(0x7Fu, bits, 9));  // [1,2)
  float u = fmaxf(fmaf(vf, 2.0f, -3.0f), -0.99999994f);
  float t = fmaf(-u, u, 1.0f);          // 1 - u^2  (> 0 after clamp)
  float l2 = __log2f(t);                // w = -ln t = l2 * -ln2
  float p;
  if (__builtin_expect(l2 <= -7.2134752f, 0)) {  // w >= 5
    float w = l2 * -0.69314718f;
    float s = sqrtf(w) - 3.0f;
    p = -0.000200214257f;
    p = fmaf(p, s, 0.000100950558f);
    p = fmaf(p, s, 0.00134934322f);
    p = fmaf(p, s, -0.00367342844f);
    p = fmaf(p, s, 0.00573950773f);
    p = fmaf(p, s, -0.0076224613f);
    p = fmaf(p, s, 0.00943887047f);
    p = fmaf(p, s, 1.00167406f);
    p = fmaf(p, s, 2.83297682f);
  } else {
    float a = fmaf(l2, -0.69314718f, -2.5f);  // w - 2.5
    p = 0.00021858087f;
    p = fmaf(p, a, -0.00125372503f);
    p = fmaf(p, a, -0.00417768164f);
    p = fmaf(p, a, 0.246640727f);
    p = fmaf(p, a, 1.50140941f);
  }
  // nm = 1 + C * p * u,  C = 0.01*sqrt(2)
  return fmaf(p, u * 0.014142135623730951f, 1.0f);
}

// ---------------------------------------------------------------------------
// Device globals: precomputed per-tid A fragments (f16) + noise key
// g_afrag[tid][16]: halfs 0..7 = af0 (k=0..31 slice), 8..15 = af1 (k=32..63)
// ---------------------------------------------------------------------------
__device__ __align__(16) _Float16 g_afrag[256 * 16];
__device__ uint32_t g_key[2];

// ---------------------------------------------------------------------------
// Setup: fold 3 rotations into one real 64-pt circulant kernel g[64] (fp32,
// double only for twiddles), then emit per-tid MFMA A-fragments + threefry key.
// (validated R5: A[row][k] = g[(row-k)&63] — convolution, not correlation)
// ---------------------------------------------------------------------------
__global__ void setup_kernel(const float* __restrict__ rx,
                             const float* __restrict__ ry,
                             const float* __restrict__ rz) {
  __shared__ float cre[3][64], cim[3][64];
  __shared__ float Gr[64], Gi[64];
  __shared__ float twc[64], tws[64];
  __shared__ float gs[64];
  const int t = threadIdx.x;  // 256 threads

  if (t < 32) {
    const float* ps[3] = {rx, ry, rz};
    for (int a = 0; a < 3; ++a) {
      float s = 0.0f;
      for (int r = 0; r < 16; ++r) s += ps[a][t * 16 + r];
      float h = 0.5f * s;  // theta[:32] * 0.5
      float ch = cosf(h), sh = sinf(h);
      if (a < 2) {  // rx, ry: repeat(cos(half), 2) -> real diag
        cre[a][2 * t] = ch;     cim[a][2 * t] = 0.0f;
        cre[a][2 * t + 1] = ch; cim[a][2 * t + 1] = 0.0f;
      } else {      // rz: [exp(-ih), exp(+ih)] interleaved
        cre[2][2 * t] = ch;     cim[2][2 * t] = -sh;
        cre[2][2 * t + 1] = ch; cim[2][2 * t + 1] = sh;
      }
    }
  }
  if (t < 64) {
    double ang = (2.0 * 3.14159265358979323846 / 64.0) * (double)t;
    twc[t] = (float)cos(ang);
    tws[t] = (float)sin(ang);
  }
  __syncthreads();

  if (t < 64) {  // Hermitian-symmetrize each spectrum, complex product
    const int k = t, kn = (64 - k) & 63;
    float pr = 1.0f, pi = 0.0f;
    for (int a = 0; a < 3; ++a) {
      float cr = 0.5f * (cre[a][k] + cre[a][kn]);
      float ci = 0.5f * (cim[a][k] - cim[a][kn]);
      float nr = pr * cr - pi * ci;
      float ni = pr * ci + pi * cr;
      pr = nr; pi = ni;
    }
    Gr[k] = pr; Gi[k] = pi;
  }
  __syncthreads();

  if (t < 64) {  // g[m] = Re( ifft(G)[m] )
    const int mi = t;
    float s = 0.0f;
    for (int k = 0; k < 64; ++k) {
      int idx = (k * mi) & 63;
      s = fmaf(Gr[k], twc[idx], s);
      s = fmaf(-Gi[k], tws[idx], s);
    }
    gs[mi] = s * (1.0f / 64.0f);
  }
  __syncthreads();

  {
    const int w = t >> 6, lane = t & 63, quad = lane >> 4, m = lane & 15;
    const int r0 = 16 * w + m - 8 * quad;
#pragma unroll
    for (int j = 0; j < 8; ++j) {
      g_afrag[t * 16 + j]     = (_Float16)gs[(r0 - j) & 63];
      g_afrag[t * 16 + 8 + j] = (_Float16)gs[(r0 - 32 - j) & 63];
    }
  }

  if (t == 0) {
    uint32_t o0, o1;
    threefry2x32(0u, 42u, 0u, 0u, o0, o1);  // ka = split(key(42))[0]
    g_key[0] = o0; g_key[1] = o1;
  }
}

// ---------------------------------------------------------------------------
// Main: per (b,t) row. Y = Gm . X via f16 MFMA (fp32 accum); JAX-exact amp
// noise + L2-normalize directly on MFMA C-layout (col=lane&15, row=quad*4+r).
//
// R6 restructure: the RNG is data-independent, so it is computed BEFORE the
// barrier, split in two halves:
//   issue 8 global loads -> nm[0..7] (~700 VALU covers VMEM latency)
//   -> cvt+ds_write      -> nm[8..15] (covers barrier skew / A-frag loads)
//   -> barrier -> MFMA -> apply nm -> reduce -> store
// Previously loads/barrier/MFMA all preceded the RNG with nothing to hide
// their latency under (VALUBusy 85.8%, Occupancy 59.6% at R5).
// ---------------------------------------------------------------------------
__global__ __launch_bounds__(256, 8) void qmain(const float* __restrict__ x,
                                                float* __restrict__ out) {
  __shared__ __align__(16) _Float16 Xt[64 * 72];  // [d][q], row stride 72 halfs
  __shared__ float red[4];
  const int tid = threadIdx.x;
  const int row = blockIdx.x;  // 0..4095 = b*T + t
  const int lane = tid & 63;
  const int w = tid >> 6;      // wave id: output rows 16w..16w+15
  const int quad = lane >> 4;  // 0..3
  const int m = lane & 15;     // A's m index == D's col index

  // phase 0: issue the row's global loads (float2 over d, 8 q's per thread)
  const float* xr = x + (size_t)row * 4096;
  const int d0 = (tid & 31) * 2;   // this thread: d rows d0, d0+1
  const int q0 = (tid >> 5) * 8;   // q columns q0..q0+7
  float2 v[8];
#pragma unroll
  for (int s = 0; s < 8; ++s) v[s] = *(const float2*)(xr + (q0 + s) * 64 + d0);

  const uint32_t ka0 = g_key[0], ka1 = g_key[1];
  const uint32_t idxbase = ((uint32_t)row << 12) +
                           (uint32_t)(((16 * w + 4 * quad) << 6) + m);

  // phase 1a: first half of the noise multipliers while loads are in flight
  float nm[16];
#pragma unroll
  for (int c = 0; c < 2; ++c)
#pragma unroll
    for (int r = 0; r < 4; ++r)
      nm[c * 4 + r] = noise_mult(ka0, ka1, idxbase + (uint32_t)(r * 64 + 16 * c));

  // phase 1b: cvt f16 + transposed LDS staging (2 x 16B-aligned b128 writes;
  // write lane stride = 72 dw == 8 banks -> 2-way phase conflict ~1%, accepted)
  {
    union { _Float16 h[8]; uint4 u; } r0, r1;
#pragma unroll
    for (int s = 0; s < 8; ++s) { r0.h[s] = (_Float16)v[s].x; r1.h[s] = (_Float16)v[s].y; }
    *(uint4*)&Xt[d0 * 72 + q0] = r0.u;
    *(uint4*)&Xt[(d0 + 1) * 72 + q0] = r1.u;
  }

  // A fragments: 2 coalesced 16B loads, issued here so their latency hides
  // under phase 1c (only needed at the MFMAs)
  const half8* at = (const half8*)g_afrag;
  half8 af0 = at[2 * tid];
  half8 af1 = at[2 * tid + 1];

  // phase 1c: second half of the noise multipliers before the barrier
#pragma unroll
  for (int c = 2; c < 4; ++c)
#pragma unroll
    for (int r = 0; r < 4; ++r)
      nm[c * 4 + r] = noise_mult(ka0, ka1, idxbase + (uint32_t)(r * 64 + 16 * c));

  __syncthreads();

  // 8 MFMAs: acc[c] covers Y[16w+4quad+r][16c+m]
  floatx4 acc[4];
#pragma unroll
  for (int c = 0; c < 4; ++c) {
    const _Float16* bp = &Xt[(16 * c + m) * 72 + 8 * quad];
    half8 b0 = *(const half8*)bp;          // k = 0..31 slice
    half8 b1 = *(const half8*)(bp + 32);   // k = 32..63 slice
    acc[c] = (floatx4){0.0f, 0.0f, 0.0f, 0.0f};
    acc[c] = __builtin_amdgcn_mfma_f32_16x16x32_f16(af0, b0, acc[c], 0, 0, 0);
    acc[c] = __builtin_amdgcn_mfma_f32_16x16x32_f16(af1, b1, acc[c], 0, 0, 0);
  }

  // apply noise + sum of squares, directly on C-layout elements
  // element (c, r): (q, d) = (16w + 4quad + r, 16c + m)
  float wv[16];
  float ssum = 0.0f;
#pragma unroll
  for (int c = 0; c < 4; ++c) {
#pragma unroll
    for (int r = 0; r < 4; ++r) {
      float val = nm[c * 4 + r] * acc[c][r];
      ssum = fmaf(val, val, ssum);
      wv[c * 4 + r] = val;
    }
  }

  // block reduction of sum of squares
#pragma unroll
  for (int off = 32; off >= 1; off >>= 1) ssum += __shfl_xor(ssum, off, 64);
  if (lane == 0) red[w] = ssum;
  __syncthreads();
  const float total = red[0] + red[1] + red[2] + red[3];
  const float scale = 1.0f / (sqrtf(total) + 1e-8f);

  // stores: one base + 16 immediate-offset dword stores (|.| folds into v_mul)
  float* ob = out + (size_t)row * 4096 + (size_t)(((16 * w + 4 * quad) << 6) + m);
#pragma unroll
  for (int c = 0; c < 4; ++c)
#pragma unroll
    for (int r = 0; r < 4; ++r)
      ob[r * 64 + 16 * c] = fabsf(wv[c * 4 + r]) * scale;
}

// ---------------------------------------------------------------------------
extern "C" void kernel_launch(void* const* d_in, const int* in_sizes, int n_in,
                              void* d_out, int out_size, void* d_ws, size_t ws_size,
                              hipStream_t stream) {
  const float* x  = (const float*)d_in[0];
  const float* rx = (const float*)d_in[1];
  const float* ry = (const float*)d_in[2];
  const float* rz = (const float*)d_in[3];
  float* out = (float*)d_out;

  setup_kernel<<<1, 256, 0, stream>>>(rx, ry, rz);
  qmain<<<4096, 256, 0, stream>>>(x, out);
}